// Round 4
// baseline (490.276 us; speedup 1.0000x reference)
//
#include <hip/hip_runtime.h>
#include <math.h>

#define N_TOK   16384
#define D_MODEL 4096
#define N_EXP   16
#define N_SEL   4
#define WELEM   (N_EXP * D_MODEL)   // 65536 per weight matrix
#define KSPLIT  8
#define KRANGE  (D_MODEL / KSPLIT)  // 512
#define NSTEP   (KRANGE / 32)       // 16

typedef __bf16 bf16x8 __attribute__((ext_vector_type(8)));
typedef float  f32x4  __attribute__((ext_vector_type(4)));

#define MFMA(a, b, c) __builtin_amdgcn_mfma_f32_16x16x32_bf16((a), (b), (c), 0, 0, 0)

// ---------------------------------------------------------------------------
// Split w1/wn into bf16 (hi, mid, lo) triplets: w ≈ hi + mid + lo.
// Layout in wbuf: [w1hi][w1mid][w1lo][wnhi][wnmid][wnlo].
// ---------------------------------------------------------------------------
__global__ __launch_bounds__(256) void wprep_kernel(const float* __restrict__ w1,
                                                    const float* __restrict__ wn,
                                                    __bf16* __restrict__ wbuf)
{
    const int i = blockIdx.x * 256 + threadIdx.x;   // 0..65535
    {
        const float v = w1[i];
        const __bf16 h = (__bf16)v;  const float r1 = v - (float)h;
        const __bf16 m = (__bf16)r1; const float r2 = r1 - (float)m;
        wbuf[i] = h; wbuf[WELEM + i] = m; wbuf[2 * WELEM + i] = (__bf16)r2;
    }
    {
        const float v = wn[i];
        const __bf16 h = (__bf16)v;  const float r1 = v - (float)h;
        const __bf16 m = (__bf16)r1; const float r2 = r1 - (float)m;
        wbuf[3 * WELEM + i] = h; wbuf[4 * WELEM + i] = m; wbuf[5 * WELEM + i] = (__bf16)r2;
    }
}

__device__ __forceinline__ void split3(const float4 a, const float4 b,
                                       bf16x8& h, bf16x8& m, bf16x8& lo)
{
    const float v[8] = {a.x, a.y, a.z, a.w, b.x, b.y, b.z, b.w};
    #pragma unroll
    for (int j = 0; j < 8; ++j) {
        const __bf16 hh = (__bf16)v[j]; const float r1 = v[j] - (float)hh;
        const __bf16 mm = (__bf16)r1;   const float r2 = r1 - (float)mm;
        h[j] = hh; m[j] = mm; lo[j] = (__bf16)r2;
    }
}

// ---------------------------------------------------------------------------
// GEMM kernel: dots[ks][t][0..15] = x[t, krange]·w1[e, krange] (partial),
//              dots[ks][t][16..31] likewise for wn.
// Block = 4 waves sharing ONE k-range (weights L1-shared), 16 tokens each.
// Grid = 256 token-groups x 8 k-splits = 2048 blocks.
// A-frag (weights): A[m=lane&15][k=q*8+j]; B-frag (x): B[k=q*8+j][n=lane&15];
// C/D: col(token)=lane&15, row(expert)=q*4+reg.
// Register double-buffer: step s+1's 8 loads issued before computing step s.
// ---------------------------------------------------------------------------
__global__ __launch_bounds__(256, 4) void gemm_kernel(
    const float* __restrict__ x, const __bf16* __restrict__ wbuf,
    float* __restrict__ dots)
{
    const int tid = threadIdx.x;
    const int l   = tid & 63;
    const int w   = tid >> 6;
    const int ml  = l & 15;      // expert-row (A) / token (B,C)
    const int q   = l >> 4;      // k-group
    const int tb  = blockIdx.x >> 3;
    const int ks  = blockIdx.x & 7;
    const int kbase = ks * KRANGE;
    const int trow  = tb * 64 + w * 16 + ml;

    const __bf16* wp[6] = {wbuf,             wbuf + WELEM,     wbuf + 2 * WELEM,
                           wbuf + 3 * WELEM, wbuf + 4 * WELEM, wbuf + 5 * WELEM};

    const size_t xoff = (size_t)trow * D_MODEL + kbase + q * 8;
    const int    woff = ml * D_MODEL + kbase + q * 8;

    f32x4 c1 = {0.f, 0.f, 0.f, 0.f};
    f32x4 c2 = {0.f, 0.f, 0.f, 0.f};

    float4 xa[2], xb[2];
    bf16x8 wr[2][6];

    // preload step 0
    xa[0] = *(const float4*)(x + xoff);
    xb[0] = *(const float4*)(x + xoff + 4);
    #pragma unroll
    for (int a = 0; a < 6; ++a) wr[0][a] = *(const bf16x8*)(wp[a] + woff);

    #pragma unroll
    for (int s = 0; s < NSTEP; ++s) {
        const int cur = s & 1, nxt = cur ^ 1;
        if (s + 1 < NSTEP) {
            const int ko = (s + 1) * 32;
            xa[nxt] = *(const float4*)(x + xoff + ko);
            xb[nxt] = *(const float4*)(x + xoff + ko + 4);
            #pragma unroll
            for (int a = 0; a < 6; ++a)
                wr[nxt][a] = *(const bf16x8*)(wp[a] + woff + ko);
        }

        bf16x8 xh, xm, xl;
        split3(xa[cur], xb[cur], xh, xm, xl);

        c1 = MFMA(wr[cur][0], xh, c1); c1 = MFMA(wr[cur][0], xm, c1);
        c1 = MFMA(wr[cur][1], xh, c1); c1 = MFMA(wr[cur][0], xl, c1);
        c1 = MFMA(wr[cur][2], xh, c1); c1 = MFMA(wr[cur][1], xm, c1);
        c2 = MFMA(wr[cur][3], xh, c2); c2 = MFMA(wr[cur][3], xm, c2);
        c2 = MFMA(wr[cur][4], xh, c2); c2 = MFMA(wr[cur][3], xl, c2);
        c2 = MFMA(wr[cur][5], xh, c2); c2 = MFMA(wr[cur][4], xm, c2);
    }

    float* dst = dots + ((size_t)ks * N_TOK + trow) * 32 + q * 4;
    *(float4*)(dst)      = make_float4(c1[0], c1[1], c1[2], c1[3]);
    *(float4*)(dst + 16) = make_float4(c2[0], c2[1], c2[2], c2[3]);
}

// ---------------------------------------------------------------------------
// Per-token gating epilogue (verified in R1/R2).
// ---------------------------------------------------------------------------
__global__ __launch_bounds__(256) void epilogue_kernel(
    const float* __restrict__ dots, const float* __restrict__ w2,
    const float* __restrict__ noise, float* __restrict__ out,
    float* __restrict__ g_imp, float* __restrict__ g_load)
{
    __shared__ float s_imp[N_EXP];
    __shared__ float s_ld[N_EXP];
    const int tid = threadIdx.x;
    if (tid < N_EXP) { s_imp[tid] = 0.f; s_ld[tid] = 0.f; }
    __syncthreads();

    const int t = blockIdx.x * 256 + tid;

    float4 a[8];
    #pragma unroll
    for (int j = 0; j < 8; ++j)
        a[j] = ((const float4*)dots)[(size_t)t * 8 + j];
    #pragma unroll
    for (int ds = 1; ds < KSPLIT; ++ds) {
        #pragma unroll
        for (int j = 0; j < 8; ++j) {
            float4 b = ((const float4*)dots)[((size_t)ds * N_TOK + t) * 8 + j];
            a[j].x += b.x; a[j].y += b.y; a[j].z += b.z; a[j].w += b.w;
        }
    }
    float dot[32];
    #pragma unroll
    for (int j = 0; j < 8; ++j) {
        dot[4 * j + 0] = a[j].x; dot[4 * j + 1] = a[j].y;
        dot[4 * j + 2] = a[j].z; dot[4 * j + 3] = a[j].w;
    }

    float th[N_EXP], nc[N_EXP];
    #pragma unroll
    for (int e = 0; e < N_EXP; ++e) th[e] = tanhf(dot[e]);
    #pragma unroll
    for (int e = 0; e < N_EXP; ++e) {
        const float v = dot[N_EXP + e];
        nc[e] = fmaxf(v, 0.f) + log1pf(expf(-fabsf(v))) + 0.01f;
    }

    float lg[N_EXP];
    #pragma unroll
    for (int f = 0; f < N_EXP; ++f) {
        float s = 0.f;
        #pragma unroll
        for (int e = 0; e < N_EXP; ++e) s = fmaf(th[e], w2[f * 16 + e], s);
        lg[f] = s;
    }

    float ln[N_EXP], v[N_EXP];
    {
        const float4* nz = (const float4*)(noise + (size_t)t * 16);
        const float4 n0 = nz[0], n1 = nz[1], n2 = nz[2], n3 = nz[3];
        const float nzv[16] = {n0.x, n0.y, n0.z, n0.w, n1.x, n1.y, n1.z, n1.w,
                               n2.x, n2.y, n2.z, n2.w, n3.x, n3.y, n3.z, n3.w};
        #pragma unroll
        for (int e = 0; e < N_EXP; ++e) {
            ln[e] = nzv[e] * nc[e];
            v[e]  = lg[e] + ln[e];
        }
    }

    // top-5 selection (ties -> lowest index, matching lax.top_k)
    float tv[5]; int ti[5];
    #pragma unroll
    for (int j = 0; j < 5; ++j) {
        float best = -INFINITY; int bi = 0;
        #pragma unroll
        for (int e = 0; e < N_EXP; ++e) {
            bool taken = false;
            #pragma unroll
            for (int jj = 0; jj < 5; ++jj)
                if (jj < j) taken = taken || (ti[jj] == e);
            if (!taken && v[e] > best) { best = v[e]; bi = e; }
        }
        tv[j] = best; ti[j] = bi;
    }

    const float mx = tv[0];
    float ex[4], ssum = 0.f;
    #pragma unroll
    for (int j = 0; j < 4; ++j) { ex[j] = expf(tv[j] - mx); ssum += ex[j]; }
    const float inv = 1.f / ssum;
    float sc[4];
    #pragma unroll
    for (int j = 0; j < 4; ++j) sc[j] = ex[j] * inv;

    #pragma unroll
    for (int j = 0; j < 4; ++j) atomicAdd(&s_imp[ti[j]], sc[j]);

    const float thr_in = tv[4], thr_out = tv[3];
    #pragma unroll
    for (int e = 0; e < N_EXP; ++e) {
        const bool  is_in = ln[e] > thr_in;
        const float thr   = is_in ? thr_in : thr_out;
        const float z     = (lg[e] - thr) / nc[e];
        const float prob  = 0.5f * (1.f + erff(z * 0.70710678118654752f));
        atomicAdd(&s_ld[e], prob);
    }

    ((float4*)out)[t] = make_float4((float)ti[0], (float)ti[1],
                                    (float)ti[2], (float)ti[3]);
    ((float4*)(out + N_TOK * N_SEL))[t] = make_float4(sc[0], sc[1], sc[2], sc[3]);

    __syncthreads();
    if (tid < N_EXP) {
        atomicAdd(&g_imp[tid], s_imp[tid]);
        atomicAdd(&g_load[tid], s_ld[tid]);
    }
}

// ---------------------------------------------------------------------------
// gate loss = lambda * (cv2(importance) + cv2(load))
// ---------------------------------------------------------------------------
__global__ void loss_kernel(const float* __restrict__ g_imp,
                            const float* __restrict__ g_load,
                            float* __restrict__ out)
{
    if (threadIdx.x == 0 && blockIdx.x == 0) {
        double mi = 0.0, ml = 0.0;
        for (int e = 0; e < N_EXP; ++e) { mi += g_imp[e]; ml += g_load[e]; }
        mi /= N_EXP; ml /= N_EXP;
        double vi = 0.0, vl = 0.0;
        for (int e = 0; e < N_EXP; ++e) {
            const double di = g_imp[e] - mi;  vi += di * di;
            const double dl = g_load[e] - ml; vl += dl * dl;
        }
        vi /= (N_EXP - 1); vl /= (N_EXP - 1);
        const double ci = vi / (mi * mi + 1e-10);
        const double cl = vl / (ml * ml + 1e-10);
        out[N_TOK * N_SEL * 2] = (float)(0.01 * (ci + cl));
    }
}

// ---------------------------------------------------------------------------
extern "C" void kernel_launch(void* const* d_in, const int* in_sizes, int n_in,
                              void* d_out, int out_size, void* d_ws, size_t ws_size,
                              hipStream_t stream)
{
    const float* x     = (const float*)d_in[0];
    const float* w1    = (const float*)d_in[1];
    const float* w2    = (const float*)d_in[2];
    const float* wn    = (const float*)d_in[3];
    const float* noise = (const float*)d_in[4];
    float* out = (float*)d_out;

    __bf16* wbuf   = (__bf16*)d_ws;                             // 768 KB @ 0
    float*  g_imp  = (float*)((char*)d_ws + (1 << 20));         // @ 1 MB
    float*  g_load = g_imp + N_EXP;
    float*  dots   = (float*)((char*)d_ws + (2 << 20));         // 16 MB @ 2 MB

    hipMemsetAsync(g_imp, 0, 2 * N_EXP * sizeof(float), stream);

    wprep_kernel<<<WELEM / 256, 256, 0, stream>>>(w1, wn, wbuf);
    gemm_kernel<<<256 * KSPLIT, 256, 0, stream>>>(x, wbuf, dots);
    epilogue_kernel<<<N_TOK / 256, 256, 0, stream>>>(dots, w2, noise, out,
                                                     g_imp, g_load);
    loss_kernel<<<1, 64, 0, stream>>>(g_imp, g_load, out);
}